// Round 16
// baseline (710.881 us; speedup 1.0000x reference)
//
#include <hip/hip_runtime.h>
#include <hip/hip_bf16.h>

#define B_ 64
#define N_ 207
#define T_ 24
#define D_ 128
#define H_ 8
#define MROWS (B_*N_*T_)             // 317952 = 128*2484
#define SELEMS ((size_t)MROWS * D_)  // 40697856
#define NBLK_FB 768
#define BNROWS_FB 414
#define NBLK_FUSED (MROWS/128)       // 2484 gate tiles
#define EPS_ 1e-5f

typedef __attribute__((ext_vector_type(8))) short s16x8;   // 8 bf16 (4 VGPR)
typedef __attribute__((ext_vector_type(4))) float f32x4;   // MFMA acc

#define MFMA16(a,b,c) __builtin_amdgcn_mfma_f32_16x16x32_bf16(a,b,c,0,0,0)

__device__ __forceinline__ float bfu2f(unsigned short u) {
  return __uint_as_float(((unsigned int)u) << 16);
}
// native v_cvt (RNE)
__device__ __forceinline__ unsigned short f2bfu(float f) {
  union { __hip_bfloat16 h; unsigned short u; } cv;
  cv.h = __float2bfloat16(f);
  return cv.u;
}
__device__ __forceinline__ unsigned int packbf2(float lo, float hi) {
  return (unsigned int)f2bfu(lo) | ((unsigned int)f2bfu(hi) << 16);
}

// ---------------------------------------------------------------------------
// Weight cast: Wq|Wk|Wv|Wo|Wgcn (128x128 each) | Wgate (128x256) -> bf16
// ---------------------------------------------------------------------------
__global__ __launch_bounds__(256) void k_wcast(
    const float* __restrict__ Wq, const float* __restrict__ Wk,
    const float* __restrict__ Wv, const float* __restrict__ Wo,
    const float* __restrict__ Wgcn, const float* __restrict__ Wgate,
    unsigned short* __restrict__ out)
{
  const int idx4 = (blockIdx.x * 256 + threadIdx.x) * 4;
  if (idx4 >= 114688) return;
  const float* src; int off;
  if      (idx4 < 16384) { src = Wq;    off = idx4; }
  else if (idx4 < 32768) { src = Wk;    off = idx4 - 16384; }
  else if (idx4 < 49152) { src = Wv;    off = idx4 - 32768; }
  else if (idx4 < 65536) { src = Wo;    off = idx4 - 49152; }
  else if (idx4 < 81920) { src = Wgcn;  off = idx4 - 65536; }
  else                   { src = Wgate; off = idx4 - 81920; }
  const float4 v = *(const float4*)(src + off);
  ushort4 u;
  u.x = f2bfu(v.x); u.y = f2bfu(v.y); u.z = f2bfu(v.z); u.w = f2bfu(v.w);
  *(ushort4*)(out + idx4) = u;
}

// ---------------------------------------------------------------------------
// GCN coalesced chunk loader (R15-proven)
// ---------------------------------------------------------------------------
__device__ __forceinline__ void gcn_load_c(
    const float* __restrict__ mbase, const float* __restrict__ hbase,
    int m0, int rn, int cc, int ch,
    float mv[16], float hv[16])
{
  const int n = ch*32 + rn;
  const bool ok = (n < N_);
  const size_t ns = (size_t)(ok ? n : 0);
  {
    const float* r = mbase + ns*N_ + m0 + cc;
    #pragma unroll
    for (int j = 0; j < 4; ++j) {
      const int mg = m0 + cc + j*4;
      if (mg + 3 < N_) {
        const float4 x = *(const float4*)(r + j*4);
        mv[j*4+0]=x.x; mv[j*4+1]=x.y; mv[j*4+2]=x.z; mv[j*4+3]=x.w;
      } else {
        #pragma unroll
        for (int e = 0; e < 4; ++e)
          mv[j*4+e] = ((mg + e) < N_) ? r[j*4+e] : 0.f;
      }
    }
    if (!ok) {
      #pragma unroll
      for (int e = 0; e < 16; ++e) mv[e] = 0.f;
    }
  }
  {
    const float* r = hbase + ns*(T_*D_) + cc;
    #pragma unroll
    for (int j = 0; j < 4; ++j) {
      const float4 x = *(const float4*)(r + j*4);
      hv[j*4+0]=x.x; hv[j*4+1]=x.y; hv[j*4+2]=x.z; hv[j*4+3]=x.w;
    }
    if (!ok) {
      #pragma unroll
      for (int e = 0; e < 16; ++e) hv[e] = 0.f;
    }
  }
}

// ---------------------------------------------------------------------------
// Fused GCN branch (R15-proven: coalesced loads + XOR-swizzled staging)
// ---------------------------------------------------------------------------
__global__ __launch_bounds__(256) void k_gcn2(
    const float* __restrict__ hidden, const float* __restrict__ matrix,
    const unsigned short* __restrict__ Wgcnb, const float* __restrict__ bgcn,
    unsigned short* __restrict__ gcn)
{
  __shared__ __align__(16) unsigned char smem[40960];
  unsigned short* GsAll = (unsigned short*)smem;

  const int tid = threadIdx.x;
  const int w = tid >> 6, l = tid & 63;
  const int lr = l & 15, lg = l >> 4;
  const int m0 = blockIdx.x * 128;
  const int by = (int)blockIdx.y;
  const int b = by / T_, t = by % T_;

  const int rn = tid >> 3;
  const int cc = (tid & 7) * 16;

  const float* mbase = matrix + (size_t)(b*T_ + t)*N_*N_;
  const float* hbase = hidden + (size_t)b*N_*T_*D_ + (size_t)t*D_;

  f32x4 acc1[2][8];
  #pragma unroll
  for (int mt = 0; mt < 2; mt++)
    #pragma unroll
    for (int nt = 0; nt < 8; nt++)
      #pragma unroll
      for (int e = 0; e < 4; e++) acc1[mt][nt][e] = 0.f;

  float mv[16], hv[16];
  gcn_load_c(mbase, hbase, m0, rn, cc, 0, mv, hv);

  const int swzA0 = ((2*w)     & 3) << 3;
  const int swzA1 = ((2*w + 1) & 3) << 3;

  #pragma unroll
  for (int ch = 0; ch < 7; ++ch) {
    unsigned char* base = smem + ((ch & 1) ? 20480 : 0);
    unsigned short* M16w = (unsigned short*)base;
    unsigned short* H16w = (unsigned short*)(base + 10240);
    #pragma unroll
    for (int e = 0; e < 16; ++e) {
      const int mloc = cc + e;
      const int ks = rn ^ (((mloc >> 4) & 3) << 3);
      M16w[mloc*40 + ks] = f2bfu(mv[e]);
      H16w[mloc*40 + ks] = f2bfu(hv[e]);
    }
    if (ch < 6)
      gcn_load_c(mbase, hbase, m0, rn, cc, ch + 1, mv, hv);
    __syncthreads();
    const unsigned short* M16 = (const unsigned short*)base;
    const unsigned short* H16 = (const unsigned short*)(base + 10240);
    const s16x8 af0 = *(const s16x8*)(M16 + (size_t)(w*32 +  0 + lr)*40 + (lg*8 ^ swzA0));
    const s16x8 af1 = *(const s16x8*)(M16 + (size_t)(w*32 + 16 + lr)*40 + (lg*8 ^ swzA1));
    #pragma unroll
    for (int nt = 0; nt < 8; ++nt) {
      const int swzB = (nt & 3) << 3;
      const s16x8 bf = *(const s16x8*)(H16 + (size_t)(nt*16 + lr)*40 + (lg*8 ^ swzB));
      acc1[0][nt] = MFMA16(af0, bf, acc1[0][nt]);
      acc1[1][nt] = MFMA16(af1, bf, acc1[1][nt]);
    }
  }

  __syncthreads();
  unsigned short* gs = GsAll + (size_t)w * (32*136);
  #pragma unroll
  for (int nt = 0; nt < 8; nt++)
    #pragma unroll
    for (int mt = 0; mt < 2; mt++)
      #pragma unroll
      for (int r = 0; r < 4; r++)
        gs[(mt*16 + lg*4 + r)*136 + nt*16 + lr] = f2bfu(acc1[mt][nt][r]);

  f32x4 acc2[2][8];
  #pragma unroll
  for (int mt = 0; mt < 2; mt++)
    #pragma unroll
    for (int nt = 0; nt < 8; nt++)
      #pragma unroll
      for (int e = 0; e < 4; e++) acc2[mt][nt][e] = 0.f;

  #pragma unroll
  for (int ks = 0; ks < 4; ++ks) {
    const s16x8 a0 = *(const s16x8*)(gs + (size_t)( 0 + lr)*136 + ks*32 + lg*8);
    const s16x8 a1 = *(const s16x8*)(gs + (size_t)(16 + lr)*136 + ks*32 + lg*8);
    #pragma unroll
    for (int nt = 0; nt < 8; ++nt) {
      const s16x8 bf = *(const s16x8*)(Wgcnb + (size_t)(nt*16 + lr)*D_ + ks*32 + lg*8);
      acc2[0][nt] = MFMA16(a0, bf, acc2[0][nt]);
      acc2[1][nt] = MFMA16(a1, bf, acc2[1][nt]);
    }
  }

  #pragma unroll
  for (int nt = 0; nt < 8; nt++) {
    const float bsc = bgcn[nt*16 + lr];
    #pragma unroll
    for (int mt = 0; mt < 2; mt++)
      #pragma unroll
      for (int r = 0; r < 4; r++)
        gs[(mt*16 + lg*4 + r)*136 + nt*16 + lr] = f2bfu(acc2[mt][nt][r] + bsc);
  }
  const size_t Obase = ((size_t)b*N_ + (m0 + w*32))*(size_t)(T_*D_) + (size_t)t*D_;
  #pragma unroll
  for (int p = 0; p < 8; p++) {
    const int c = p*64 + l;
    const int row = c >> 4, c8 = (c & 15) * 8;
    const int gm = m0 + w*32 + row;
    if (gm < N_) {
      const s16x8 v = *(const s16x8*)(gs + row*136 + c8);
      *(s16x8*)(gcn + Obase + (size_t)row*(T_*D_) + c8) = v;
    }
  }
}

// ---------------------------------------------------------------------------
// Fused attention v5: R10 chain, LDS aliased down to 3 buffers (37.9 KB ->
// 4 blocks/CU). Pure re-mapping, no new chain links, 4 barriers as before:
//   X staged into Qs (Q overwrites after af-read barrier);
//   ctx -> Ks (wave's K cols dead after its own bkf read, same wave);
//   Wo reads cf from Ks, writes out to Qs (Q dead).
// Stale K rows 24..31 only feed unstored output rows (values bounded, no NaN).
// ---------------------------------------------------------------------------
__global__ __launch_bounds__(256) void k_attn3(
    const float* __restrict__ hidden,
    const unsigned short* __restrict__ Wqb, const unsigned short* __restrict__ Wkb,
    const unsigned short* __restrict__ Wvb, const unsigned short* __restrict__ Wob,
    const float* __restrict__ bq, const float* __restrict__ bk,
    const float* __restrict__ bv, const float* __restrict__ bo,
    unsigned short* __restrict__ attnO)
{
  __shared__ __align__(16) unsigned short Qs[32*136];   // X, then Q, then Wo out
  __shared__ __align__(16) unsigned short Ks[32*136];   // K, then ctx
  __shared__ __align__(16) unsigned short Vt[128*40];   // V transposed [d][t]
  __shared__ __align__(16) unsigned short Ps[4][32*40]; // per-wave P (A-layout)
  const int tid = threadIdx.x;
  const int w = tid >> 6, l = tid & 63;
  const int lr = l & 15, lg = l >> 4;
  const size_t bn = blockIdx.x;
  const float* X = hidden + bn * (size_t)(T_*D_);

  // stage X -> Qs (bf16), rows 24..31 zero
  for (int i = tid; i < 32*16; i += 256) {
    const int row = i >> 4, g8 = (i & 15) * 8;
    if (row < T_) {
      const float4 a  = *(const float4*)(X + (size_t)row*D_ + g8);
      const float4 b2 = *(const float4*)(X + (size_t)row*D_ + g8 + 4);
      uint4 u;
      u.x = packbf2(a.x, a.y);   u.y = packbf2(a.z, a.w);
      u.z = packbf2(b2.x, b2.y); u.w = packbf2(b2.z, b2.w);
      *(uint4*)&Qs[row*136 + g8] = u;
    } else {
      *(uint4*)&Qs[row*136 + g8] = make_uint4(0,0,0,0);
    }
  }
  __syncthreads();

  // A-frags of X (all waves read all of Qs here; barrier after)
  s16x8 af[2][4];
  #pragma unroll
  for (int mt = 0; mt < 2; mt++)
    #pragma unroll
    for (int ks = 0; ks < 4; ks++)
      af[mt][ks] = *(const s16x8*)&Qs[(mt*16 + lr)*136 + ks*32 + lg*8];
  __syncthreads();   // after this, Qs is free for Q writes

  // ---- Q/K/V projections: wave w computes cols 32w..32w+31 (wave-local use)
  const unsigned short* Wp[3] = {Wqb, Wkb, Wvb};
  const float*          bp[3] = {bq, bk, bv};
  #pragma unroll
  for (int o = 0; o < 3; o++) {
    f32x4 acc[2][2];
    #pragma unroll
    for (int mt = 0; mt < 2; mt++)
      #pragma unroll
      for (int nt = 0; nt < 2; nt++)
        #pragma unroll
        for (int e = 0; e < 4; e++) acc[mt][nt][e] = 0.f;
    #pragma unroll
    for (int ks = 0; ks < 4; ks++) {
      #pragma unroll
      for (int nt = 0; nt < 2; nt++) {
        const s16x8 bf = *(const s16x8*)(Wp[o] + (size_t)(w*32 + nt*16 + lr)*D_ + ks*32 + lg*8);
        acc[0][nt] = MFMA16(af[0][ks], bf, acc[0][nt]);
        acc[1][nt] = MFMA16(af[1][ks], bf, acc[1][nt]);
      }
    }
    #pragma unroll
    for (int nt = 0; nt < 2; nt++) {
      const float bb = bp[o][w*32 + nt*16 + lr];
      #pragma unroll
      for (int mt = 0; mt < 2; mt++)
        #pragma unroll
        for (int r = 0; r < 4; r++) {
          const unsigned short hvs = f2bfu(acc[mt][nt][r] + bb);
          const int trow = mt*16 + lg*4 + r;           // t index
          const int dcol = w*32 + nt*16 + lr;          // output dim
          if (o == 0)      Qs[trow*136 + dcol] = hvs;
          else if (o == 1) Ks[trow*136 + dcol] = hvs;
          else             Vt[dcol*40 + trow] = hvs;   // transposed
        }
    }
  }

  // ---- per-head attention, fully wave-local; ctx -> Ks (own cols, dead K)
  unsigned short* Pw = Ps[w];
  s16x8 zv;
  #pragma unroll
  for (int e = 0; e < 8; e++) zv[e] = 0;
  #pragma unroll
  for (int hi = 0; hi < 2; hi++) {
    const int hh = 2*w + hi;
    s16x8 aq[2], bkf[2];
    #pragma unroll
    for (int mt = 0; mt < 2; mt++) {
      s16x8 tv = zv;
      if (lg < 2) tv = *(const s16x8*)&Qs[(mt*16 + lr)*136 + hh*16 + lg*8];
      aq[mt] = tv;
    }
    #pragma unroll
    for (int nt = 0; nt < 2; nt++) {
      s16x8 tv = zv;
      if (lg < 2) tv = *(const s16x8*)&Ks[(nt*16 + lr)*136 + hh*16 + lg*8];
      bkf[nt] = tv;
    }
    f32x4 accS[2][2];
    #pragma unroll
    for (int mt = 0; mt < 2; mt++)
      #pragma unroll
      for (int nt = 0; nt < 2; nt++) {
        f32x4 z4; z4[0]=0.f; z4[1]=0.f; z4[2]=0.f; z4[3]=0.f;
        accS[mt][nt] = MFMA16(aq[mt], bkf[nt], z4);
      }
    // softmax per row t (C layout: row = mt*16+lg*4+r, col s = nt*16+lr)
    #pragma unroll
    for (int mt = 0; mt < 2; mt++) {
      #pragma unroll
      for (int r = 0; r < 4; r++) {
        const int t = mt*16 + lg*4 + r;
        const bool m0b = (lr <= t), m1b = (16 + lr <= t);
        float e0 = m0b ? __expf(0.25f * accS[mt][0][r]) : 0.f;
        float e1 = m1b ? __expf(0.25f * accS[mt][1][r]) : 0.f;
        float den = e0 + e1;
        den += __shfl_xor(den, 1);
        den += __shfl_xor(den, 2);
        den += __shfl_xor(den, 4);
        den += __shfl_xor(den, 8);
        const float rd = 1.f / den;
        Pw[t*40 + lr]      = f2bfu(e0 * rd);
        Pw[t*40 + 16 + lr] = f2bfu(e1 * rd);
      }
    }
    // PV: ctx[t, d] = sum_s P[t,s] V[s,d]
    s16x8 ap[2];
    #pragma unroll
    for (int mt = 0; mt < 2; mt++)
      ap[mt] = *(const s16x8*)&Pw[(mt*16 + lr)*40 + lg*8];
    const s16x8 bvf = *(const s16x8*)&Vt[(hh*16 + lr)*40 + lg*8];
    f32x4 accP[2];
    #pragma unroll
    for (int mt = 0; mt < 2; mt++) {
      f32x4 z4; z4[0]=0.f; z4[1]=0.f; z4[2]=0.f; z4[3]=0.f;
      accP[mt] = MFMA16(ap[mt], bvf, z4);
    }
    // ctx -> Ks cols hh*16.. (wave-local; K cols for head hh dead after bkf)
    #pragma unroll
    for (int mt = 0; mt < 2; mt++)
      #pragma unroll
      for (int r = 0; r < 4; r++) {
        const int t = mt*16 + lg*4 + r;
        if (t < T_) Ks[t*136 + hh*16 + lr] = f2bfu(accP[mt][r]);
      }
  }
  __syncthreads();   // ctx (Ks) complete across waves

  // ---- Wo GEMM: A = ctx (Ks), out -> Qs (wave-local cols), store rows<24
  s16x8 cf[2][4];
  #pragma unroll
  for (int mt = 0; mt < 2; mt++)
    #pragma unroll
    for (int ks = 0; ks < 4; ks++)
      cf[mt][ks] = *(const s16x8*)&Ks[(mt*16 + lr)*136 + ks*32 + lg*8];
  f32x4 acc2[2][2];
  #pragma unroll
  for (int mt = 0; mt < 2; mt++)
    #pragma unroll
    for (int nt = 0; nt < 2; nt++)
      #pragma unroll
      for (int e = 0; e < 4; e++) acc2[mt][nt][e] = 0.f;
  #pragma unroll
  for (int ks = 0; ks < 4; ks++) {
    #pragma unroll
    for (int nt = 0; nt < 2; nt++) {
      const s16x8 bf = *(const s16x8*)(Wob + (size_t)(w*32 + nt*16 + lr)*D_ + ks*32 + lg*8);
      acc2[0][nt] = MFMA16(cf[0][ks], bf, acc2[0][nt]);
      acc2[1][nt] = MFMA16(cf[1][ks], bf, acc2[1][nt]);
    }
  }
  #pragma unroll
  for (int nt = 0; nt < 2; nt++) {
    const float bb = bo[w*32 + nt*16 + lr];
    #pragma unroll
    for (int mt = 0; mt < 2; mt++)
      #pragma unroll
      for (int r = 0; r < 4; r++)
        Qs[(mt*16 + lg*4 + r)*136 + w*32 + nt*16 + lr] =
            f2bfu(acc2[mt][nt][r] + bb);
  }
  __syncthreads();
  unsigned short* O = attnO + bn * (size_t)(T_*D_);
  for (int i = tid; i < 24*16; i += 256) {
    const int row = i >> 4, g8 = (i & 15) * 8;
    *(s16x8*)(O + (size_t)row*D_ + g8) = *(const s16x8*)&Qs[row*136 + g8];
  }
}

// ---------------------------------------------------------------------------
// Gate GEMM. MODE 0: stats only. MODE 1: fp32 g write (fallback).
// MODE 2: bf16 g write (coalesced via per-wave LDS repack) + stats.
// ---------------------------------------------------------------------------
template<int MODE>
__global__ __launch_bounds__(256) void k_gate(
    const unsigned short* __restrict__ A0, const unsigned short* __restrict__ A1,
    const unsigned short* __restrict__ Wb, const float* __restrict__ bias,
    float* __restrict__ OutF, unsigned short* __restrict__ OutB,
    float* __restrict__ psum, float* __restrict__ psq)
{
  __shared__ float lbs[4*128], lbq[4*128];
  __shared__ __align__(16) unsigned short lb[4][32*136];  // MODE 2 only
  const int tid = threadIdx.x;
  const int w = tid >> 6, l = tid & 63;
  const int lr = l & 15, lg = l >> 4;
  const size_t m0 = (size_t)blockIdx.x * 128 + w * 32;

  f32x4 acc[2][8];
  #pragma unroll
  for (int mt = 0; mt < 2; mt++)
    #pragma unroll
    for (int nt = 0; nt < 8; nt++)
      #pragma unroll
      for (int e = 0; e < 4; e++) acc[mt][nt][e] = 0.f;

  #pragma unroll
  for (int ks = 0; ks < 8; ks++) {
    const unsigned short* Asrc = (ks >= 4) ? A1 : A0;
    const int kk = (ks >= 4) ? ks - 4 : ks;
    const s16x8 a0 = *(const s16x8*)(Asrc + (m0 +  0 + lr)*D_ + kk*32 + lg*8);
    const s16x8 a1 = *(const s16x8*)(Asrc + (m0 + 16 + lr)*D_ + kk*32 + lg*8);
    #pragma unroll
    for (int nt = 0; nt < 8; nt++) {
      const s16x8 bf = *(const s16x8*)(Wb + (size_t)(nt*16 + lr)*256 + ks*32 + lg*8);
      acc[0][nt] = MFMA16(a0, bf, acc[0][nt]);
      acc[1][nt] = MFMA16(a1, bf, acc[1][nt]);
    }
  }

  #pragma unroll
  for (int nt = 0; nt < 8; nt++) {
    const float b = bias[nt*16 + lr];
    float s = 0.f, q = 0.f;
    #pragma unroll
    for (int mt = 0; mt < 2; mt++)
      #pragma unroll
      for (int r = 0; r < 4; r++) {
        const float v = acc[mt][nt][r] + b;
        if (MODE == 1) OutF[(m0 + mt*16 + lg*4 + r)*D_ + nt*16 + lr] = v;
        if (MODE == 2) lb[w][(mt*16 + lg*4 + r)*136 + nt*16 + lr] = f2bfu(v);
        if (MODE != 1) { s += v; q += v*v; }
      }
    if (MODE != 1) {
      s += __shfl_xor(s, 16); s += __shfl_xor(s, 32);
      q += __shfl_xor(q, 16); q += __shfl_xor(q, 32);
      if (lg == 0) {
        lbs[w*128 + nt*16 + lr] = s;
        lbq[w*128 + nt*16 + lr] = q;
      }
    }
  }
  if (MODE == 2) {
    #pragma unroll
    for (int p = 0; p < 8; p++) {
      const int c = p*64 + l;
      const int row = c >> 4, c8 = (c & 15) * 8;
      const s16x8 v = *(const s16x8*)&lb[w][row*136 + c8];
      *(s16x8*)(OutB + (m0 + row)*D_ + c8) = v;
    }
  }
  if (MODE != 1) {
    __syncthreads();
    if (tid < 128) {
      const float ss = lbs[tid] + lbs[128 + tid] + lbs[256 + tid] + lbs[384 + tid];
      const float qq = lbq[tid] + lbq[128 + tid] + lbq[256 + tid] + lbq[384 + tid];
      psum[(size_t)blockIdx.x*128 + tid] = ss;
      psq [(size_t)blockIdx.x*128 + tid] = qq;
    }
  }
}

// ---------------------------------------------------------------------------
// Tier-2 fused final: recompute gate GEMM + BN + blend (g never hits HBM).
// ---------------------------------------------------------------------------
__global__ __launch_bounds__(256) void k_final2(
    const unsigned short* __restrict__ A0, const unsigned short* __restrict__ A1,
    const unsigned short* __restrict__ Wb, const float* __restrict__ bias,
    const float* __restrict__ scalev, const float* __restrict__ shiftv,
    float* __restrict__ Out)
{
  __shared__ __align__(16) unsigned short lb[4][32*136];
  const int tid = threadIdx.x;
  const int w = tid >> 6, l = tid & 63;
  const int lr = l & 15, lg = l >> 4;
  const size_t m0 = (size_t)blockIdx.x * 128 + w * 32;

  f32x4 acc[2][8];
  #pragma unroll
  for (int mt = 0; mt < 2; mt++)
    #pragma unroll
    for (int nt = 0; nt < 8; nt++)
      #pragma unroll
      for (int e = 0; e < 4; e++) acc[mt][nt][e] = 0.f;

  #pragma unroll
  for (int ks = 0; ks < 8; ks++) {
    const unsigned short* Asrc = (ks >= 4) ? A1 : A0;
    const int kk = (ks >= 4) ? ks - 4 : ks;
    const s16x8 a0 = *(const s16x8*)(Asrc + (m0 +  0 + lr)*D_ + kk*32 + lg*8);
    const s16x8 a1 = *(const s16x8*)(Asrc + (m0 + 16 + lr)*D_ + kk*32 + lg*8);
    #pragma unroll
    for (int nt = 0; nt < 8; nt++) {
      const s16x8 bf = *(const s16x8*)(Wb + (size_t)(nt*16 + lr)*256 + ks*32 + lg*8);
      acc[0][nt] = MFMA16(a0, bf, acc[0][nt]);
      acc[1][nt] = MFMA16(a1, bf, acc[1][nt]);
    }
  }

  #pragma unroll
  for (int nt = 0; nt < 8; nt++) {
    const float b = bias[nt*16 + lr];
    #pragma unroll
    for (int mt = 0; mt < 2; mt++)
      #pragma unroll
      for (int r = 0; r < 4; r++)
        lb[w][(mt*16 + lg*4 + r)*136 + nt*16 + lr] = f2bfu(acc[mt][nt][r] + b);
  }
  #pragma unroll
  for (int p = 0; p < 8; p++) {
    const int c = p*64 + l;
    const int row = c >> 4, c8 = (c & 15) * 8;
    const size_t grow = m0 + row;
    const s16x8 g8  = *(const s16x8*)&lb[w][row*136 + c8];
    const s16x8 gc8 = *(const s16x8*)(A0 + grow*D_ + c8);
    const s16x8 at8 = *(const s16x8*)(A1 + grow*D_ + c8);
    const float4 sc0 = *(const float4*)(scalev + c8);
    const float4 sc1 = *(const float4*)(scalev + c8 + 4);
    const float4 sh0 = *(const float4*)(shiftv + c8);
    const float4 sh1 = *(const float4*)(shiftv + c8 + 4);
    const float scv[8] = {sc0.x,sc0.y,sc0.z,sc0.w,sc1.x,sc1.y,sc1.z,sc1.w};
    const float shv[8] = {sh0.x,sh0.y,sh0.z,sh0.w,sh1.x,sh1.y,sh1.z,sh1.w};
    float o[8];
    #pragma unroll
    for (int e = 0; e < 8; e++) {
      const float y = bfu2f((unsigned short)g8[e]) * scv[e] + shv[e];
      const float z = 1.f / (1.f + __expf(-y));
      o[e] = z * bfu2f((unsigned short)gc8[e])
           + (1.f - z) * bfu2f((unsigned short)at8[e]);
    }
    float* orow = Out + grow*D_ + c8;
    *(float4*)orow       = make_float4(o[0], o[1], o[2], o[3]);
    *(float4*)(orow + 4) = make_float4(o[4], o[5], o[6], o[7]);
  }
}

// ---------------------------------------------------------------------------
// Tier-3 final: z = sigmoid(g_bf16*scale+shift); out = z*gcn + (1-z)*attn
// ---------------------------------------------------------------------------
__global__ __launch_bounds__(256) void k_finalz(
    const unsigned short* __restrict__ gb,
    const unsigned short* __restrict__ gcn, const unsigned short* __restrict__ attn,
    const float* __restrict__ scalev, const float* __restrict__ shiftv,
    float* __restrict__ Out)
{
  const size_t tot8 = SELEMS >> 3;
  for (size_t i8 = (size_t)blockIdx.x*blockDim.x + threadIdx.x; i8 < tot8;
       i8 += (size_t)gridDim.x*blockDim.x) {
    const int c8 = (int)(i8 & 15) * 8;
    const s16x8 g8  = ((const s16x8*)gb)[i8];
    const s16x8 gc8 = ((const s16x8*)gcn)[i8];
    const s16x8 at8 = ((const s16x8*)attn)[i8];
    const float4 sc0 = *(const float4*)(scalev + c8);
    const float4 sc1 = *(const float4*)(scalev + c8 + 4);
    const float4 sh0 = *(const float4*)(shiftv + c8);
    const float4 sh1 = *(const float4*)(shiftv + c8 + 4);
    const float scv[8] = {sc0.x,sc0.y,sc0.z,sc0.w,sc1.x,sc1.y,sc1.z,sc1.w};
    const float shv[8] = {sh0.x,sh0.y,sh0.z,sh0.w,sh1.x,sh1.y,sh1.z,sh1.w};
    float o[8];
    #pragma unroll
    for (int e = 0; e < 8; e++) {
      const float y = bfu2f((unsigned short)g8[e]) * scv[e] + shv[e];
      const float z = 1.f / (1.f + __expf(-y));
      o[e] = z * bfu2f((unsigned short)gc8[e])
           + (1.f - z) * bfu2f((unsigned short)at8[e]);
    }
    float* orow = Out + i8*8;
    *(float4*)orow       = make_float4(o[0], o[1], o[2], o[3]);
    *(float4*)(orow + 4) = make_float4(o[4], o[5], o[6], o[7]);
  }
}

// ---------------------------------------------------------------------------
// Fallback BN stats + finals (tier 1)
// ---------------------------------------------------------------------------
__global__ __launch_bounds__(256) void k_bnstats(
    const float* __restrict__ g, float* __restrict__ psum, float* __restrict__ psq)
{
  const int tid = threadIdx.x;
  const int c4 = (tid & 31) * 4, sub = tid >> 5;
  const size_t r0 = (size_t)blockIdx.x * BNROWS_FB;
  float4 s = make_float4(0.f,0.f,0.f,0.f), q = make_float4(0.f,0.f,0.f,0.f);
  for (int i = sub; i < BNROWS_FB; i += 8) {
    const float4 x = *(const float4*)(g + (r0 + i)*D_ + c4);
    s.x += x.x; s.y += x.y; s.z += x.z; s.w += x.w;
    q.x += x.x*x.x; q.y += x.y*x.y; q.z += x.z*x.z; q.w += x.w*x.w;
  }
  __shared__ float ls[8*128], lq[8*128];
  *(float4*)&ls[sub*128 + c4] = s;
  *(float4*)&lq[sub*128 + c4] = q;
  __syncthreads();
  if (tid < 128) {
    float ss = 0.f, qq = 0.f;
    #pragma unroll
    for (int k = 0; k < 8; k++) { ss += ls[k*128 + tid]; qq += lq[k*128 + tid]; }
    psum[(size_t)blockIdx.x*128 + tid] = ss;
    psq [(size_t)blockIdx.x*128 + tid] = qq;
  }
}

__global__ __launch_bounds__(1024) void k_bnfinal(
    const float* __restrict__ psum, const float* __restrict__ psq, int nblk,
    const float* __restrict__ gamma, const float* __restrict__ beta,
    float* __restrict__ scalev, float* __restrict__ shiftv)
{
  const int tid = threadIdx.x;
  const int sub = tid >> 7, ch = tid & 127;
  float s = 0.f, q = 0.f;
  for (int i = sub; i < nblk; i += 8) {
    s += psum[(size_t)i*128 + ch];
    q += psq [(size_t)i*128 + ch];
  }
  __shared__ float ls[8*128], lq[8*128];
  ls[sub*128 + ch] = s; lq[sub*128 + ch] = q;
  __syncthreads();
  if (tid < 128) {
    float ss = 0.f, qq = 0.f;
    #pragma unroll
    for (int k = 0; k < 8; k++) { ss += ls[k*128 + tid]; qq += lq[k*128 + tid]; }
    const float mean = ss / (float)MROWS;
    const float var  = qq / (float)MROWS - mean*mean;
    const float istd = rsqrtf(var + EPS_);
    const float sc = istd * gamma[tid];
    scalev[tid] = sc;
    shiftv[tid] = beta[tid] - mean * sc;
  }
}

__global__ __launch_bounds__(256) void k_final(
    float* __restrict__ g,
    const unsigned short* __restrict__ gcn, const unsigned short* __restrict__ attn,
    const float* __restrict__ scalev, const float* __restrict__ shiftv)
{
  const size_t tot4 = SELEMS >> 2;
  for (size_t i4 = (size_t)blockIdx.x*blockDim.x + threadIdx.x; i4 < tot4;
       i4 += (size_t)gridDim.x*blockDim.x) {
    const int c4 = (int)(i4 & 31) * 4;
    const float4 gv = ((const float4*)g)[i4];
    const ushort4 gc = ((const ushort4*)gcn)[i4];
    const ushort4 at = ((const ushort4*)attn)[i4];
    const float4 sc = *(const float4*)(scalev + c4);
    const float4 sh = *(const float4*)(shiftv + c4);
    float4 outv;
    { const float y = gv.x*sc.x + sh.x;
      const float z = 1.f/(1.f + __expf(-y));
      outv.x = z*bfu2f(gc.x) + (1.f - z)*bfu2f(at.x); }
    { const float y = gv.y*sc.y + sh.y;
      const float z = 1.f/(1.f + __expf(-y));
      outv.y = z*bfu2f(gc.y) + (1.f - z)*bfu2f(at.y); }
    { const float y = gv.z*sc.z + sh.z;
      const float z = 1.f/(1.f + __expf(-y));
      outv.z = z*bfu2f(gc.z) + (1.f - z)*bfu2f(at.z); }
    { const float y = gv.w*sc.w + sh.w;
      const float z = 1.f/(1.f + __expf(-y));
      outv.w = z*bfu2f(gc.w) + (1.f - z)*bfu2f(at.w); }
    ((float4*)g)[i4] = outv;
  }
}

// ---------------------------------------------------------------------------
extern "C" void kernel_launch(void* const* d_in, const int* in_sizes, int n_in,
                              void* d_out, int out_size, void* d_ws, size_t ws_size,
                              hipStream_t stream)
{
  (void)in_sizes; (void)n_in; (void)out_size;
  const float* hidden = (const float*)d_in[0];
  const float* matrix = (const float*)d_in[1];
  const float* Wq   = (const float*)d_in[2];  const float* bq    = (const float*)d_in[3];
  const float* Wk   = (const float*)d_in[4];  const float* bk    = (const float*)d_in[5];
  const float* Wv   = (const float*)d_in[6];  const float* bv    = (const float*)d_in[7];
  const float* Wo   = (const float*)d_in[8];  const float* bo    = (const float*)d_in[9];
  const float* Wgcn = (const float*)d_in[10]; const float* bgcn  = (const float*)d_in[11];
  const float* Wgate= (const float*)d_in[12]; const float* bgate = (const float*)d_in[13];
  const float* gamma= (const float*)d_in[14]; const float* beta  = (const float*)d_in[15];
  float* out = (float*)d_out;

  unsigned short* WB = (unsigned short*)d_ws;
  unsigned short* Wqb    = WB;
  unsigned short* Wkb    = WB + 16384;
  unsigned short* Wvb    = WB + 32768;
  unsigned short* Wob    = WB + 49152;
  unsigned short* Wgcnb  = WB + 65536;
  unsigned short* Wgateb = WB + 81920;
  unsigned short* X1     = WB + 114688;
  unsigned short* X2     = X1 + SELEMS;
  float* psum    = (float*)(X2 + SELEMS);

  const size_t base_bytes = (size_t)114688*2 + 2*SELEMS*2;
  const size_t fused_bytes = base_bytes + ((size_t)NBLK_FUSED*128*2 + 256)*4;
  const size_t tier3_bytes = fused_bytes + SELEMS*2;
  const bool fused = (ws_size >= fused_bytes);
  const bool tier3 = (ws_size >= tier3_bytes);
  const int nblk = fused ? NBLK_FUSED : NBLK_FB;
  float* psq     = psum + (size_t)nblk*128;
  float* scalev  = psq  + (size_t)nblk*128;
  float* shiftv  = scalev + 128;
  unsigned short* gbuf = (unsigned short*)(shiftv + 128);   // tier-3 g bf16

  k_wcast<<<112, 256, 0, stream>>>(Wq, Wk, Wv, Wo, Wgcn, Wgate, WB);
  k_gcn2 <<<dim3(2, B_*T_), 256, 0, stream>>>(hidden, matrix, Wgcnb, bgcn, X2);
  k_attn3<<<B_*N_, 256, 0, stream>>>(hidden, Wqb, Wkb, Wvb, Wob,
                                     bq, bk, bv, bo, X1);
  if (tier3) {
    k_gate<2><<<MROWS/128, 256, 0, stream>>>(X2, X1, Wgateb, bgate,
                                             nullptr, gbuf, psum, psq);
    k_bnfinal<<<1, 1024, 0, stream>>>(psum, psq, nblk, gamma, beta, scalev, shiftv);
    k_finalz<<<2048, 256, 0, stream>>>(gbuf, X2, X1, scalev, shiftv, out);
  } else if (fused) {
    k_gate<0><<<MROWS/128, 256, 0, stream>>>(X2, X1, Wgateb, bgate,
                                             nullptr, nullptr, psum, psq);
    k_bnfinal<<<1, 1024, 0, stream>>>(psum, psq, nblk, gamma, beta, scalev, shiftv);
    k_final2<<<MROWS/128, 256, 0, stream>>>(X2, X1, Wgateb, bgate,
                                            scalev, shiftv, out);
  } else {
    k_gate<1><<<MROWS/128, 256, 0, stream>>>(X2, X1, Wgateb, bgate,
                                             out, nullptr, psum, psq);
    k_bnstats<<<NBLK_FB, 256, 0, stream>>>(out, psum, psq);
    k_bnfinal<<<1, 1024, 0, stream>>>(psum, psq, nblk, gamma, beta, scalev, shiftv);
    k_final<<<2048, 256, 0, stream>>>(out, X2, X1, scalev, shiftv);
  }
}

// Round 17
// 692.611 us; speedup vs baseline: 1.0264x; 1.0264x over previous
//
#include <hip/hip_runtime.h>
#include <hip/hip_bf16.h>

#define B_ 64
#define N_ 207
#define T_ 24
#define D_ 128
#define H_ 8
#define MROWS (B_*N_*T_)             // 317952 = 128*2484
#define SELEMS ((size_t)MROWS * D_)  // 40697856
#define NBLK_FB 768
#define BNROWS_FB 414
#define NBLK_FUSED (MROWS/128)       // 2484 gate tiles
#define EPS_ 1e-5f

typedef __attribute__((ext_vector_type(8))) short s16x8;   // 8 bf16 (4 VGPR)
typedef __attribute__((ext_vector_type(4))) float f32x4;   // MFMA acc

#define MFMA16(a,b,c) __builtin_amdgcn_mfma_f32_16x16x32_bf16(a,b,c,0,0,0)

__device__ __forceinline__ float bfu2f(unsigned short u) {
  return __uint_as_float(((unsigned int)u) << 16);
}
// native v_cvt (RNE)
__device__ __forceinline__ unsigned short f2bfu(float f) {
  union { __hip_bfloat16 h; unsigned short u; } cv;
  cv.h = __float2bfloat16(f);
  return cv.u;
}
__device__ __forceinline__ unsigned int packbf2(float lo, float hi) {
  return (unsigned int)f2bfu(lo) | ((unsigned int)f2bfu(hi) << 16);
}

// ---------------------------------------------------------------------------
// Weight cast: Wq|Wk|Wv|Wo|Wgcn (128x128 each) | Wgate (128x256) -> bf16
// ---------------------------------------------------------------------------
__global__ __launch_bounds__(256) void k_wcast(
    const float* __restrict__ Wq, const float* __restrict__ Wk,
    const float* __restrict__ Wv, const float* __restrict__ Wo,
    const float* __restrict__ Wgcn, const float* __restrict__ Wgate,
    unsigned short* __restrict__ out)
{
  const int idx4 = (blockIdx.x * 256 + threadIdx.x) * 4;
  if (idx4 >= 114688) return;
  const float* src; int off;
  if      (idx4 < 16384) { src = Wq;    off = idx4; }
  else if (idx4 < 32768) { src = Wk;    off = idx4 - 16384; }
  else if (idx4 < 49152) { src = Wv;    off = idx4 - 32768; }
  else if (idx4 < 65536) { src = Wo;    off = idx4 - 49152; }
  else if (idx4 < 81920) { src = Wgcn;  off = idx4 - 65536; }
  else                   { src = Wgate; off = idx4 - 81920; }
  const float4 v = *(const float4*)(src + off);
  ushort4 u;
  u.x = f2bfu(v.x); u.y = f2bfu(v.y); u.z = f2bfu(v.z); u.w = f2bfu(v.w);
  *(ushort4*)(out + idx4) = u;
}

// ---------------------------------------------------------------------------
// GCN coalesced chunk loader (R15-proven)
// ---------------------------------------------------------------------------
__device__ __forceinline__ void gcn_load_c(
    const float* __restrict__ mbase, const float* __restrict__ hbase,
    int m0, int rn, int cc, int ch,
    float mv[16], float hv[16])
{
  const int n = ch*32 + rn;
  const bool ok = (n < N_);
  const size_t ns = (size_t)(ok ? n : 0);
  {
    const float* r = mbase + ns*N_ + m0 + cc;
    #pragma unroll
    for (int j = 0; j < 4; ++j) {
      const int mg = m0 + cc + j*4;
      if (mg + 3 < N_) {
        const float4 x = *(const float4*)(r + j*4);
        mv[j*4+0]=x.x; mv[j*4+1]=x.y; mv[j*4+2]=x.z; mv[j*4+3]=x.w;
      } else {
        #pragma unroll
        for (int e = 0; e < 4; ++e)
          mv[j*4+e] = ((mg + e) < N_) ? r[j*4+e] : 0.f;
      }
    }
    if (!ok) {
      #pragma unroll
      for (int e = 0; e < 16; ++e) mv[e] = 0.f;
    }
  }
  {
    const float* r = hbase + ns*(T_*D_) + cc;
    #pragma unroll
    for (int j = 0; j < 4; ++j) {
      const float4 x = *(const float4*)(r + j*4);
      hv[j*4+0]=x.x; hv[j*4+1]=x.y; hv[j*4+2]=x.z; hv[j*4+3]=x.w;
    }
    if (!ok) {
      #pragma unroll
      for (int e = 0; e < 16; ++e) hv[e] = 0.f;
    }
  }
}

// ---------------------------------------------------------------------------
// Fused GCN branch (R15-proven: coalesced loads + XOR-swizzled staging)
// ---------------------------------------------------------------------------
__global__ __launch_bounds__(256) void k_gcn2(
    const float* __restrict__ hidden, const float* __restrict__ matrix,
    const unsigned short* __restrict__ Wgcnb, const float* __restrict__ bgcn,
    unsigned short* __restrict__ gcn)
{
  __shared__ __align__(16) unsigned char smem[40960];
  unsigned short* GsAll = (unsigned short*)smem;

  const int tid = threadIdx.x;
  const int w = tid >> 6, l = tid & 63;
  const int lr = l & 15, lg = l >> 4;
  const int m0 = blockIdx.x * 128;
  const int by = (int)blockIdx.y;
  const int b = by / T_, t = by % T_;

  const int rn = tid >> 3;
  const int cc = (tid & 7) * 16;

  const float* mbase = matrix + (size_t)(b*T_ + t)*N_*N_;
  const float* hbase = hidden + (size_t)b*N_*T_*D_ + (size_t)t*D_;

  f32x4 acc1[2][8];
  #pragma unroll
  for (int mt = 0; mt < 2; mt++)
    #pragma unroll
    for (int nt = 0; nt < 8; nt++)
      #pragma unroll
      for (int e = 0; e < 4; e++) acc1[mt][nt][e] = 0.f;

  float mv[16], hv[16];
  gcn_load_c(mbase, hbase, m0, rn, cc, 0, mv, hv);

  const int swzA0 = ((2*w)     & 3) << 3;
  const int swzA1 = ((2*w + 1) & 3) << 3;

  #pragma unroll
  for (int ch = 0; ch < 7; ++ch) {
    unsigned char* base = smem + ((ch & 1) ? 20480 : 0);
    unsigned short* M16w = (unsigned short*)base;
    unsigned short* H16w = (unsigned short*)(base + 10240);
    #pragma unroll
    for (int e = 0; e < 16; ++e) {
      const int mloc = cc + e;
      const int ks = rn ^ (((mloc >> 4) & 3) << 3);
      M16w[mloc*40 + ks] = f2bfu(mv[e]);
      H16w[mloc*40 + ks] = f2bfu(hv[e]);
    }
    if (ch < 6)
      gcn_load_c(mbase, hbase, m0, rn, cc, ch + 1, mv, hv);
    __syncthreads();
    const unsigned short* M16 = (const unsigned short*)base;
    const unsigned short* H16 = (const unsigned short*)(base + 10240);
    const s16x8 af0 = *(const s16x8*)(M16 + (size_t)(w*32 +  0 + lr)*40 + (lg*8 ^ swzA0));
    const s16x8 af1 = *(const s16x8*)(M16 + (size_t)(w*32 + 16 + lr)*40 + (lg*8 ^ swzA1));
    #pragma unroll
    for (int nt = 0; nt < 8; ++nt) {
      const int swzB = (nt & 3) << 3;
      const s16x8 bf = *(const s16x8*)(H16 + (size_t)(nt*16 + lr)*40 + (lg*8 ^ swzB));
      acc1[0][nt] = MFMA16(af0, bf, acc1[0][nt]);
      acc1[1][nt] = MFMA16(af1, bf, acc1[1][nt]);
    }
  }

  __syncthreads();
  unsigned short* gs = GsAll + (size_t)w * (32*136);
  #pragma unroll
  for (int nt = 0; nt < 8; nt++)
    #pragma unroll
    for (int mt = 0; mt < 2; mt++)
      #pragma unroll
      for (int r = 0; r < 4; r++)
        gs[(mt*16 + lg*4 + r)*136 + nt*16 + lr] = f2bfu(acc1[mt][nt][r]);

  f32x4 acc2[2][8];
  #pragma unroll
  for (int mt = 0; mt < 2; mt++)
    #pragma unroll
    for (int nt = 0; nt < 8; nt++)
      #pragma unroll
      for (int e = 0; e < 4; e++) acc2[mt][nt][e] = 0.f;

  #pragma unroll
  for (int ks = 0; ks < 4; ++ks) {
    const s16x8 a0 = *(const s16x8*)(gs + (size_t)( 0 + lr)*136 + ks*32 + lg*8);
    const s16x8 a1 = *(const s16x8*)(gs + (size_t)(16 + lr)*136 + ks*32 + lg*8);
    #pragma unroll
    for (int nt = 0; nt < 8; ++nt) {
      const s16x8 bf = *(const s16x8*)(Wgcnb + (size_t)(nt*16 + lr)*D_ + ks*32 + lg*8);
      acc2[0][nt] = MFMA16(a0, bf, acc2[0][nt]);
      acc2[1][nt] = MFMA16(a1, bf, acc2[1][nt]);
    }
  }

  #pragma unroll
  for (int nt = 0; nt < 8; nt++) {
    const float bsc = bgcn[nt*16 + lr];
    #pragma unroll
    for (int mt = 0; mt < 2; mt++)
      #pragma unroll
      for (int r = 0; r < 4; r++)
        gs[(mt*16 + lg*4 + r)*136 + nt*16 + lr] = f2bfu(acc2[mt][nt][r] + bsc);
  }
  const size_t Obase = ((size_t)b*N_ + (m0 + w*32))*(size_t)(T_*D_) + (size_t)t*D_;
  #pragma unroll
  for (int p = 0; p < 8; p++) {
    const int c = p*64 + l;
    const int row = c >> 4, c8 = (c & 15) * 8;
    const int gm = m0 + w*32 + row;
    if (gm < N_) {
      const s16x8 v = *(const s16x8*)(gs + row*136 + c8);
      *(s16x8*)(gcn + Obase + (size_t)row*(T_*D_) + c8) = v;
    }
  }
}

// ---------------------------------------------------------------------------
// Fused attention (R10/R15-proven, best measured): per (b,n) block, 4 waves,
// SEPARATE LDS buffers (aliasing falsified twice: R9 +18us, R16 +19us).
// ---------------------------------------------------------------------------
__global__ __launch_bounds__(256) void k_attn3(
    const float* __restrict__ hidden,
    const unsigned short* __restrict__ Wqb, const unsigned short* __restrict__ Wkb,
    const unsigned short* __restrict__ Wvb, const unsigned short* __restrict__ Wob,
    const float* __restrict__ bq, const float* __restrict__ bk,
    const float* __restrict__ bv, const float* __restrict__ bo,
    unsigned short* __restrict__ attnO)
{
  __shared__ __align__(16) unsigned short Xs[32*136];   // X, later ctx
  __shared__ __align__(16) unsigned short Qs[32*136];   // Q, later Wo out
  __shared__ __align__(16) unsigned short Ks[32*136];
  __shared__ __align__(16) unsigned short Vt[128*40];   // V transposed [d][t]
  __shared__ __align__(16) unsigned short Ps[4][32*40]; // per-wave P (A-layout)
  const int tid = threadIdx.x;
  const int w = tid >> 6, l = tid & 63;
  const int lr = l & 15, lg = l >> 4;
  const size_t bn = blockIdx.x;
  const float* X = hidden + bn * (size_t)(T_*D_);

  for (int i = tid; i < 32*16; i += 256) {
    const int row = i >> 4, g8 = (i & 15) * 8;
    if (row < T_) {
      const float4 a  = *(const float4*)(X + (size_t)row*D_ + g8);
      const float4 b2 = *(const float4*)(X + (size_t)row*D_ + g8 + 4);
      uint4 u;
      u.x = packbf2(a.x, a.y);   u.y = packbf2(a.z, a.w);
      u.z = packbf2(b2.x, b2.y); u.w = packbf2(b2.z, b2.w);
      *(uint4*)&Xs[row*136 + g8] = u;
    } else {
      *(uint4*)&Xs[row*136 + g8] = make_uint4(0,0,0,0);
    }
  }
  __syncthreads();

  s16x8 af[2][4];
  #pragma unroll
  for (int mt = 0; mt < 2; mt++)
    #pragma unroll
    for (int ks = 0; ks < 4; ks++)
      af[mt][ks] = *(const s16x8*)&Xs[(mt*16 + lr)*136 + ks*32 + lg*8];
  __syncthreads();   // after this, Xs is free for ctx writes

  const unsigned short* Wp[3] = {Wqb, Wkb, Wvb};
  const float*          bp[3] = {bq, bk, bv};
  #pragma unroll
  for (int o = 0; o < 3; o++) {
    f32x4 acc[2][2];
    #pragma unroll
    for (int mt = 0; mt < 2; mt++)
      #pragma unroll
      for (int nt = 0; nt < 2; nt++)
        #pragma unroll
        for (int e = 0; e < 4; e++) acc[mt][nt][e] = 0.f;
    #pragma unroll
    for (int ks = 0; ks < 4; ks++) {
      #pragma unroll
      for (int nt = 0; nt < 2; nt++) {
        const s16x8 bf = *(const s16x8*)(Wp[o] + (size_t)(w*32 + nt*16 + lr)*D_ + ks*32 + lg*8);
        acc[0][nt] = MFMA16(af[0][ks], bf, acc[0][nt]);
        acc[1][nt] = MFMA16(af[1][ks], bf, acc[1][nt]);
      }
    }
    #pragma unroll
    for (int nt = 0; nt < 2; nt++) {
      const float bb = bp[o][w*32 + nt*16 + lr];
      #pragma unroll
      for (int mt = 0; mt < 2; mt++)
        #pragma unroll
        for (int r = 0; r < 4; r++) {
          const unsigned short hvs = f2bfu(acc[mt][nt][r] + bb);
          const int trow = mt*16 + lg*4 + r;
          const int dcol = w*32 + nt*16 + lr;
          if (o == 0)      Qs[trow*136 + dcol] = hvs;
          else if (o == 1) Ks[trow*136 + dcol] = hvs;
          else             Vt[dcol*40 + trow] = hvs;
        }
    }
  }

  unsigned short* Pw = Ps[w];
  s16x8 zv;
  #pragma unroll
  for (int e = 0; e < 8; e++) zv[e] = 0;
  #pragma unroll
  for (int hi = 0; hi < 2; hi++) {
    const int hh = 2*w + hi;
    s16x8 aq[2], bkf[2];
    #pragma unroll
    for (int mt = 0; mt < 2; mt++) {
      s16x8 tv = zv;
      if (lg < 2) tv = *(const s16x8*)&Qs[(mt*16 + lr)*136 + hh*16 + lg*8];
      aq[mt] = tv;
    }
    #pragma unroll
    for (int nt = 0; nt < 2; nt++) {
      s16x8 tv = zv;
      if (lg < 2) tv = *(const s16x8*)&Ks[(nt*16 + lr)*136 + hh*16 + lg*8];
      bkf[nt] = tv;
    }
    f32x4 accS[2][2];
    #pragma unroll
    for (int mt = 0; mt < 2; mt++)
      #pragma unroll
      for (int nt = 0; nt < 2; nt++) {
        f32x4 z4; z4[0]=0.f; z4[1]=0.f; z4[2]=0.f; z4[3]=0.f;
        accS[mt][nt] = MFMA16(aq[mt], bkf[nt], z4);
      }
    #pragma unroll
    for (int mt = 0; mt < 2; mt++) {
      #pragma unroll
      for (int r = 0; r < 4; r++) {
        const int t = mt*16 + lg*4 + r;
        const bool m0b = (lr <= t), m1b = (16 + lr <= t);
        float e0 = m0b ? __expf(0.25f * accS[mt][0][r]) : 0.f;
        float e1 = m1b ? __expf(0.25f * accS[mt][1][r]) : 0.f;
        float den = e0 + e1;
        den += __shfl_xor(den, 1);
        den += __shfl_xor(den, 2);
        den += __shfl_xor(den, 4);
        den += __shfl_xor(den, 8);
        const float rd = 1.f / den;
        Pw[t*40 + lr]      = f2bfu(e0 * rd);
        Pw[t*40 + 16 + lr] = f2bfu(e1 * rd);
      }
    }
    s16x8 ap[2];
    #pragma unroll
    for (int mt = 0; mt < 2; mt++)
      ap[mt] = *(const s16x8*)&Pw[(mt*16 + lr)*40 + lg*8];
    const s16x8 bvf = *(const s16x8*)&Vt[(hh*16 + lr)*40 + lg*8];
    f32x4 accP[2];
    #pragma unroll
    for (int mt = 0; mt < 2; mt++) {
      f32x4 z4; z4[0]=0.f; z4[1]=0.f; z4[2]=0.f; z4[3]=0.f;
      accP[mt] = MFMA16(ap[mt], bvf, z4);
    }
    #pragma unroll
    for (int mt = 0; mt < 2; mt++)
      #pragma unroll
      for (int r = 0; r < 4; r++) {
        const int t = mt*16 + lg*4 + r;
        if (t < T_) Xs[t*136 + hh*16 + lr] = f2bfu(accP[mt][r]);
      }
  }
  __syncthreads();

  s16x8 cf[2][4];
  #pragma unroll
  for (int mt = 0; mt < 2; mt++)
    #pragma unroll
    for (int ks = 0; ks < 4; ks++)
      cf[mt][ks] = *(const s16x8*)&Xs[(mt*16 + lr)*136 + ks*32 + lg*8];
  f32x4 acc2[2][2];
  #pragma unroll
  for (int mt = 0; mt < 2; mt++)
    #pragma unroll
    for (int nt = 0; nt < 2; nt++)
      #pragma unroll
      for (int e = 0; e < 4; e++) acc2[mt][nt][e] = 0.f;
  #pragma unroll
  for (int ks = 0; ks < 4; ks++) {
    #pragma unroll
    for (int nt = 0; nt < 2; nt++) {
      const s16x8 bf = *(const s16x8*)(Wob + (size_t)(w*32 + nt*16 + lr)*D_ + ks*32 + lg*8);
      acc2[0][nt] = MFMA16(cf[0][ks], bf, acc2[0][nt]);
      acc2[1][nt] = MFMA16(cf[1][ks], bf, acc2[1][nt]);
    }
  }
  #pragma unroll
  for (int nt = 0; nt < 2; nt++) {
    const float bb = bo[w*32 + nt*16 + lr];
    #pragma unroll
    for (int mt = 0; mt < 2; mt++)
      #pragma unroll
      for (int r = 0; r < 4; r++)
        Qs[(mt*16 + lg*4 + r)*136 + w*32 + nt*16 + lr] =
            f2bfu(acc2[mt][nt][r] + bb);
  }
  __syncthreads();
  unsigned short* O = attnO + bn * (size_t)(T_*D_);
  for (int i = tid; i < 24*16; i += 256) {
    const int row = i >> 4, g8 = (i & 15) * 8;
    *(s16x8*)(O + (size_t)row*D_ + g8) = *(const s16x8*)&Qs[row*136 + g8];
  }
}

// ---------------------------------------------------------------------------
// Gate GEMM. MODE 0: stats only. MODE 1: fp32 g write (fallback).
// MODE 2: bf16 g write (coalesced via per-wave LDS repack) + stats.
// ---------------------------------------------------------------------------
template<int MODE>
__global__ __launch_bounds__(256) void k_gate(
    const unsigned short* __restrict__ A0, const unsigned short* __restrict__ A1,
    const unsigned short* __restrict__ Wb, const float* __restrict__ bias,
    float* __restrict__ OutF, unsigned short* __restrict__ OutB,
    float* __restrict__ psum, float* __restrict__ psq)
{
  __shared__ float lbs[4*128], lbq[4*128];
  __shared__ __align__(16) unsigned short lb[4][32*136];  // MODE 2 only
  const int tid = threadIdx.x;
  const int w = tid >> 6, l = tid & 63;
  const int lr = l & 15, lg = l >> 4;
  const size_t m0 = (size_t)blockIdx.x * 128 + w * 32;

  f32x4 acc[2][8];
  #pragma unroll
  for (int mt = 0; mt < 2; mt++)
    #pragma unroll
    for (int nt = 0; nt < 8; nt++)
      #pragma unroll
      for (int e = 0; e < 4; e++) acc[mt][nt][e] = 0.f;

  #pragma unroll
  for (int ks = 0; ks < 8; ks++) {
    const unsigned short* Asrc = (ks >= 4) ? A1 : A0;
    const int kk = (ks >= 4) ? ks - 4 : ks;
    const s16x8 a0 = *(const s16x8*)(Asrc + (m0 +  0 + lr)*D_ + kk*32 + lg*8);
    const s16x8 a1 = *(const s16x8*)(Asrc + (m0 + 16 + lr)*D_ + kk*32 + lg*8);
    #pragma unroll
    for (int nt = 0; nt < 8; nt++) {
      const s16x8 bf = *(const s16x8*)(Wb + (size_t)(nt*16 + lr)*256 + ks*32 + lg*8);
      acc[0][nt] = MFMA16(a0, bf, acc[0][nt]);
      acc[1][nt] = MFMA16(a1, bf, acc[1][nt]);
    }
  }

  #pragma unroll
  for (int nt = 0; nt < 8; nt++) {
    const float b = bias[nt*16 + lr];
    float s = 0.f, q = 0.f;
    #pragma unroll
    for (int mt = 0; mt < 2; mt++)
      #pragma unroll
      for (int r = 0; r < 4; r++) {
        const float v = acc[mt][nt][r] + b;
        if (MODE == 1) OutF[(m0 + mt*16 + lg*4 + r)*D_ + nt*16 + lr] = v;
        if (MODE == 2) lb[w][(mt*16 + lg*4 + r)*136 + nt*16 + lr] = f2bfu(v);
        if (MODE != 1) { s += v; q += v*v; }
      }
    if (MODE != 1) {
      s += __shfl_xor(s, 16); s += __shfl_xor(s, 32);
      q += __shfl_xor(q, 16); q += __shfl_xor(q, 32);
      if (lg == 0) {
        lbs[w*128 + nt*16 + lr] = s;
        lbq[w*128 + nt*16 + lr] = q;
      }
    }
  }
  if (MODE == 2) {
    #pragma unroll
    for (int p = 0; p < 8; p++) {
      const int c = p*64 + l;
      const int row = c >> 4, c8 = (c & 15) * 8;
      const s16x8 v = *(const s16x8*)&lb[w][row*136 + c8];
      *(s16x8*)(OutB + (m0 + row)*D_ + c8) = v;
    }
  }
  if (MODE != 1) {
    __syncthreads();
    if (tid < 128) {
      const float ss = lbs[tid] + lbs[128 + tid] + lbs[256 + tid] + lbs[384 + tid];
      const float qq = lbq[tid] + lbq[128 + tid] + lbq[256 + tid] + lbq[384 + tid];
      psum[(size_t)blockIdx.x*128 + tid] = ss;
      psq [(size_t)blockIdx.x*128 + tid] = qq;
    }
  }
}

// ---------------------------------------------------------------------------
// Tier-2 fused final: recompute gate GEMM + BN + blend (g never hits HBM).
// ---------------------------------------------------------------------------
__global__ __launch_bounds__(256) void k_final2(
    const unsigned short* __restrict__ A0, const unsigned short* __restrict__ A1,
    const unsigned short* __restrict__ Wb, const float* __restrict__ bias,
    const float* __restrict__ scalev, const float* __restrict__ shiftv,
    float* __restrict__ Out)
{
  __shared__ __align__(16) unsigned short lb[4][32*136];
  const int tid = threadIdx.x;
  const int w = tid >> 6, l = tid & 63;
  const int lr = l & 15, lg = l >> 4;
  const size_t m0 = (size_t)blockIdx.x * 128 + w * 32;

  f32x4 acc[2][8];
  #pragma unroll
  for (int mt = 0; mt < 2; mt++)
    #pragma unroll
    for (int nt = 0; nt < 8; nt++)
      #pragma unroll
      for (int e = 0; e < 4; e++) acc[mt][nt][e] = 0.f;

  #pragma unroll
  for (int ks = 0; ks < 8; ks++) {
    const unsigned short* Asrc = (ks >= 4) ? A1 : A0;
    const int kk = (ks >= 4) ? ks - 4 : ks;
    const s16x8 a0 = *(const s16x8*)(Asrc + (m0 +  0 + lr)*D_ + kk*32 + lg*8);
    const s16x8 a1 = *(const s16x8*)(Asrc + (m0 + 16 + lr)*D_ + kk*32 + lg*8);
    #pragma unroll
    for (int nt = 0; nt < 8; nt++) {
      const s16x8 bf = *(const s16x8*)(Wb + (size_t)(nt*16 + lr)*256 + ks*32 + lg*8);
      acc[0][nt] = MFMA16(a0, bf, acc[0][nt]);
      acc[1][nt] = MFMA16(a1, bf, acc[1][nt]);
    }
  }

  #pragma unroll
  for (int nt = 0; nt < 8; nt++) {
    const float b = bias[nt*16 + lr];
    #pragma unroll
    for (int mt = 0; mt < 2; mt++)
      #pragma unroll
      for (int r = 0; r < 4; r++)
        lb[w][(mt*16 + lg*4 + r)*136 + nt*16 + lr] = f2bfu(acc[mt][nt][r] + b);
  }
  #pragma unroll
  for (int p = 0; p < 8; p++) {
    const int c = p*64 + l;
    const int row = c >> 4, c8 = (c & 15) * 8;
    const size_t grow = m0 + row;
    const s16x8 g8  = *(const s16x8*)&lb[w][row*136 + c8];
    const s16x8 gc8 = *(const s16x8*)(A0 + grow*D_ + c8);
    const s16x8 at8 = *(const s16x8*)(A1 + grow*D_ + c8);
    const float4 sc0 = *(const float4*)(scalev + c8);
    const float4 sc1 = *(const float4*)(scalev + c8 + 4);
    const float4 sh0 = *(const float4*)(shiftv + c8);
    const float4 sh1 = *(const float4*)(shiftv + c8 + 4);
    const float scv[8] = {sc0.x,sc0.y,sc0.z,sc0.w,sc1.x,sc1.y,sc1.z,sc1.w};
    const float shv[8] = {sh0.x,sh0.y,sh0.z,sh0.w,sh1.x,sh1.y,sh1.z,sh1.w};
    float o[8];
    #pragma unroll
    for (int e = 0; e < 8; e++) {
      const float y = bfu2f((unsigned short)g8[e]) * scv[e] + shv[e];
      const float z = 1.f / (1.f + __expf(-y));
      o[e] = z * bfu2f((unsigned short)gc8[e])
           + (1.f - z) * bfu2f((unsigned short)at8[e]);
    }
    float* orow = Out + grow*D_ + c8;
    *(float4*)orow       = make_float4(o[0], o[1], o[2], o[3]);
    *(float4*)(orow + 4) = make_float4(o[4], o[5], o[6], o[7]);
  }
}

// ---------------------------------------------------------------------------
// Tier-3 final: z = sigmoid(g_bf16*scale+shift); out = z*gcn + (1-z)*attn
// ---------------------------------------------------------------------------
__global__ __launch_bounds__(256) void k_finalz(
    const unsigned short* __restrict__ gb,
    const unsigned short* __restrict__ gcn, const unsigned short* __restrict__ attn,
    const float* __restrict__ scalev, const float* __restrict__ shiftv,
    float* __restrict__ Out)
{
  const size_t tot8 = SELEMS >> 3;
  for (size_t i8 = (size_t)blockIdx.x*blockDim.x + threadIdx.x; i8 < tot8;
       i8 += (size_t)gridDim.x*blockDim.x) {
    const int c8 = (int)(i8 & 15) * 8;
    const s16x8 g8  = ((const s16x8*)gb)[i8];
    const s16x8 gc8 = ((const s16x8*)gcn)[i8];
    const s16x8 at8 = ((const s16x8*)attn)[i8];
    const float4 sc0 = *(const float4*)(scalev + c8);
    const float4 sc1 = *(const float4*)(scalev + c8 + 4);
    const float4 sh0 = *(const float4*)(shiftv + c8);
    const float4 sh1 = *(const float4*)(shiftv + c8 + 4);
    const float scv[8] = {sc0.x,sc0.y,sc0.z,sc0.w,sc1.x,sc1.y,sc1.z,sc1.w};
    const float shv[8] = {sh0.x,sh0.y,sh0.z,sh0.w,sh1.x,sh1.y,sh1.z,sh1.w};
    float o[8];
    #pragma unroll
    for (int e = 0; e < 8; e++) {
      const float y = bfu2f((unsigned short)g8[e]) * scv[e] + shv[e];
      const float z = 1.f / (1.f + __expf(-y));
      o[e] = z * bfu2f((unsigned short)gc8[e])
           + (1.f - z) * bfu2f((unsigned short)at8[e]);
    }
    float* orow = Out + i8*8;
    *(float4*)orow       = make_float4(o[0], o[1], o[2], o[3]);
    *(float4*)(orow + 4) = make_float4(o[4], o[5], o[6], o[7]);
  }
}

// ---------------------------------------------------------------------------
// Fallback BN stats + finals (tier 1)
// ---------------------------------------------------------------------------
__global__ __launch_bounds__(256) void k_bnstats(
    const float* __restrict__ g, float* __restrict__ psum, float* __restrict__ psq)
{
  const int tid = threadIdx.x;
  const int c4 = (tid & 31) * 4, sub = tid >> 5;
  const size_t r0 = (size_t)blockIdx.x * BNROWS_FB;
  float4 s = make_float4(0.f,0.f,0.f,0.f), q = make_float4(0.f,0.f,0.f,0.f);
  for (int i = sub; i < BNROWS_FB; i += 8) {
    const float4 x = *(const float4*)(g + (r0 + i)*D_ + c4);
    s.x += x.x; s.y += x.y; s.z += x.z; s.w += x.w;
    q.x += x.x*x.x; q.y += x.y*x.y; q.z += x.z*x.z; q.w += x.w*x.w;
  }
  __shared__ float ls[8*128], lq[8*128];
  *(float4*)&ls[sub*128 + c4] = s;
  *(float4*)&lq[sub*128 + c4] = q;
  __syncthreads();
  if (tid < 128) {
    float ss = 0.f, qq = 0.f;
    #pragma unroll
    for (int k = 0; k < 8; k++) { ss += ls[k*128 + tid]; qq += lq[k*128 + tid]; }
    psum[(size_t)blockIdx.x*128 + tid] = ss;
    psq [(size_t)blockIdx.x*128 + tid] = qq;
  }
}

__global__ __launch_bounds__(1024) void k_bnfinal(
    const float* __restrict__ psum, const float* __restrict__ psq, int nblk,
    const float* __restrict__ gamma, const float* __restrict__ beta,
    float* __restrict__ scalev, float* __restrict__ shiftv)
{
  const int tid = threadIdx.x;
  const int sub = tid >> 7, ch = tid & 127;
  float s = 0.f, q = 0.f;
  for (int i = sub; i < nblk; i += 8) {
    s += psum[(size_t)i*128 + ch];
    q += psq [(size_t)i*128 + ch];
  }
  __shared__ float ls[8*128], lq[8*128];
  ls[sub*128 + ch] = s; lq[sub*128 + ch] = q;
  __syncthreads();
  if (tid < 128) {
    float ss = 0.f, qq = 0.f;
    #pragma unroll
    for (int k = 0; k < 8; k++) { ss += ls[k*128 + tid]; qq += lq[k*128 + tid]; }
    const float mean = ss / (float)MROWS;
    const float var  = qq / (float)MROWS - mean*mean;
    const float istd = rsqrtf(var + EPS_);
    const float sc = istd * gamma[tid];
    scalev[tid] = sc;
    shiftv[tid] = beta[tid] - mean * sc;
  }
}

__global__ __launch_bounds__(256) void k_final(
    float* __restrict__ g,
    const unsigned short* __restrict__ gcn, const unsigned short* __restrict__ attn,
    const float* __restrict__ scalev, const float* __restrict__ shiftv)
{
  const size_t tot4 = SELEMS >> 2;
  for (size_t i4 = (size_t)blockIdx.x*blockDim.x + threadIdx.x; i4 < tot4;
       i4 += (size_t)gridDim.x*blockDim.x) {
    const int c4 = (int)(i4 & 31) * 4;
    const float4 gv = ((const float4*)g)[i4];
    const ushort4 gc = ((const ushort4*)gcn)[i4];
    const ushort4 at = ((const ushort4*)attn)[i4];
    const float4 sc = *(const float4*)(scalev + c4);
    const float4 sh = *(const float4*)(shiftv + c4);
    float4 outv;
    { const float y = gv.x*sc.x + sh.x;
      const float z = 1.f/(1.f + __expf(-y));
      outv.x = z*bfu2f(gc.x) + (1.f - z)*bfu2f(at.x); }
    { const float y = gv.y*sc.y + sh.y;
      const float z = 1.f/(1.f + __expf(-y));
      outv.y = z*bfu2f(gc.y) + (1.f - z)*bfu2f(at.y); }
    { const float y = gv.z*sc.z + sh.z;
      const float z = 1.f/(1.f + __expf(-y));
      outv.z = z*bfu2f(gc.z) + (1.f - z)*bfu2f(at.z); }
    { const float y = gv.w*sc.w + sh.w;
      const float z = 1.f/(1.f + __expf(-y));
      outv.w = z*bfu2f(gc.w) + (1.f - z)*bfu2f(at.w); }
    ((float4*)g)[i4] = outv;
  }
}

// ---------------------------------------------------------------------------
extern "C" void kernel_launch(void* const* d_in, const int* in_sizes, int n_in,
                              void* d_out, int out_size, void* d_ws, size_t ws_size,
                              hipStream_t stream)
{
  (void)in_sizes; (void)n_in; (void)out_size;
  const float* hidden = (const float*)d_in[0];
  const float* matrix = (const float*)d_in[1];
  const float* Wq   = (const float*)d_in[2];  const float* bq    = (const float*)d_in[3];
  const float* Wk   = (const float*)d_in[4];  const float* bk    = (const float*)d_in[5];
  const float* Wv   = (const float*)d_in[6];  const float* bv    = (const float*)d_in[7];
  const float* Wo   = (const float*)d_in[8];  const float* bo    = (const float*)d_in[9];
  const float* Wgcn = (const float*)d_in[10]; const float* bgcn  = (const float*)d_in[11];
  const float* Wgate= (const float*)d_in[12]; const float* bgate = (const float*)d_in[13];
  const float* gamma= (const float*)d_in[14]; const float* beta  = (const float*)d_in[15];
  float* out = (float*)d_out;

  unsigned short* WB = (unsigned short*)d_ws;
  unsigned short* Wqb    = WB;
  unsigned short* Wkb    = WB + 16384;
  unsigned short* Wvb    = WB + 32768;
  unsigned short* Wob    = WB + 49152;
  unsigned short* Wgcnb  = WB + 65536;
  unsigned short* Wgateb = WB + 81920;
  unsigned short* X1     = WB + 114688;
  unsigned short* X2     = X1 + SELEMS;
  float* psum    = (float*)(X2 + SELEMS);

  const size_t base_bytes = (size_t)114688*2 + 2*SELEMS*2;
  const size_t fused_bytes = base_bytes + ((size_t)NBLK_FUSED*128*2 + 256)*4;
  const size_t tier3_bytes = fused_bytes + SELEMS*2;
  const bool fused = (ws_size >= fused_bytes);
  const bool tier3 = (ws_size >= tier3_bytes);
  const int nblk = fused ? NBLK_FUSED : NBLK_FB;
  float* psq     = psum + (size_t)nblk*128;
  float* scalev  = psq  + (size_t)nblk*128;
  float* shiftv  = scalev + 128;
  unsigned short* gbuf = (unsigned short*)(shiftv + 128);   // tier-3 g bf16

  k_wcast<<<112, 256, 0, stream>>>(Wq, Wk, Wv, Wo, Wgcn, Wgate, WB);
  k_gcn2 <<<dim3(2, B_*T_), 256, 0, stream>>>(hidden, matrix, Wgcnb, bgcn, X2);
  k_attn3<<<B_*N_, 256, 0, stream>>>(hidden, Wqb, Wkb, Wvb, Wob,
                                     bq, bk, bv, bo, X1);
  if (tier3) {
    k_gate<2><<<MROWS/128, 256, 0, stream>>>(X2, X1, Wgateb, bgate,
                                             nullptr, gbuf, psum, psq);
    k_bnfinal<<<1, 1024, 0, stream>>>(psum, psq, nblk, gamma, beta, scalev, shiftv);
    k_finalz<<<2048, 256, 0, stream>>>(gbuf, X2, X1, scalev, shiftv, out);
  } else if (fused) {
    k_gate<0><<<MROWS/128, 256, 0, stream>>>(X2, X1, Wgateb, bgate,
                                             nullptr, nullptr, psum, psq);
    k_bnfinal<<<1, 1024, 0, stream>>>(psum, psq, nblk, gamma, beta, scalev, shiftv);
    k_final2<<<MROWS/128, 256, 0, stream>>>(X2, X1, Wgateb, bgate,
                                            scalev, shiftv, out);
  } else {
    k_gate<1><<<MROWS/128, 256, 0, stream>>>(X2, X1, Wgateb, bgate,
                                             out, nullptr, psum, psq);
    k_bnstats<<<NBLK_FB, 256, 0, stream>>>(out, psum, psq);
    k_bnfinal<<<1, 1024, 0, stream>>>(psum, psq, nblk, gamma, beta, scalev, shiftv);
    k_final<<<2048, 256, 0, stream>>>(out, X2, X1, scalev, shiftv);
  }
}